// Round 4
// baseline (227.271 us; speedup 1.0000x reference)
//
#include <hip/hip_runtime.h>

#define NB 16
#define NT 50
#define NA 5
#define NH 152
#define NW 152
#define NC 7
#define CH 70            // NA*(7+NC)
#define HW (NH*NW)       // 23104
#define AHW (NA*HW)      // 115520
#define NCELL (NB*AHW)   // 1,848,320
#define NWORDS (NCELL/32) // 57,760
#define NSUM (NCELL/1024) // 1805 exact
#define NTGT (NB*NT)      // 800
#define GRID1 (NSUM + NTGT + 1)

// fallback geometry
#define CELL_BLOCKS ((AHW + 255) / 256)   // 452
#define NBLK (CELL_BLOCKS * NB)           // 7232

// ws float-offsets
#define D_XLO 0
#define D_XHI 800
#define D_YLO 1600
#define D_YHI 2400
#define D_GW  3200
#define D_GL  4000
#define D_Q   4800
#define D_TW  5600
#define D_TL  6400
#define D_TIM 7200
#define D_TRE 8000
#define D_GX  8800
#define D_GY  9600
#define D_META 10400     // int array
#define P_CF  11264      // fallback partials
#define M_WORD 16384     // u32 mask bits
#define A_BASE 74144     // 16 x u64 accumulators (8B aligned)
#define SP_OFF 74176     // f32[NSUM] streaming partials
#define WS_NEED ((SP_OFF + NSUM) * 4)

// A slots: 0..6 winner sums (fixed), 7 nM count, 8 sub (fixed), 9 cnt, 10 done
#define FXSCALE 4194304.0   // 2^22

__device__ __forceinline__ float sp_f(float v) {
    return (v > 20.f) ? v : __logf(1.f + __expf(v));
}

__device__ __forceinline__ void prep_one(int id, const float* __restrict__ tgt,
                                         const float* __restrict__ anchors,
                                         float* __restrict__ ws) {
    int b = id / NT, t = id - b * NT;
    const float* tp = tgt + id * 7;
    float lab = tp[0], cx = tp[1], cy = tp[2], w = tp[3], l = tp[4];
    float tim = tp[5], tre = tp[6];
    float sum = lab + cx + cy + w + l + tim + tre;
    bool valid = (sum != 0.0f);
    bool validp = true;
    const float* tb = tgt + (size_t)b * NT * 7;
    for (int t2 = 0; t2 <= t; ++t2) validp = validp && (tb[t2 * 7 + 1] != 0.0f);

    float gx = cx * NW, gy = cy * NH, gw = w * NW, gl = l * NH;
    int gi = (int)gx; gi = min(max(gi, 0), NW - 1);
    int gj = (int)gy; gj = min(max(gj, 0), NH - 1);

    float agt = (gw + 1.f) * (gl + 1.f);
    float best = -1.f; int bn = 0; int am = 0;
    float aw_b = 1.f, ah_b = 1.f;
    for (int a = 0; a < NA; ++a) {
        float aw = anchors[2 * a], ah = anchors[2 * a + 1];
        float iw = fmaxf(fminf(gw, aw) + 1.f, 0.f);
        float ih = fmaxf(fminf(gl, ah) + 1.f, 0.f);
        float inter = iw * ih;
        float aan = (aw + 1.f) * (ah + 1.f);
        float iou = inter / (agt + aan - inter + 1e-16f);
        if (iou > best) { best = iou; bn = a; aw_b = aw; ah_b = ah; }
        if (iou > 0.6f) am |= (1 << a);
    }

    ws[D_XLO + id] = gx - 0.5f * gw;
    ws[D_XHI + id] = gx + 0.5f * gw;
    ws[D_YLO + id] = gy - 0.5f * gl;
    ws[D_YHI + id] = gy + 0.5f * gl;
    ws[D_GW + id]  = gw;
    ws[D_GL + id]  = gl;
    ws[D_Q + id]   = 0.375f * gw * gl;
    ws[D_TW + id]  = logf(gw / aw_b + 1e-16f);
    ws[D_TL + id]  = logf(gl / ah_b + 1e-16f);
    ws[D_TIM + id] = tim;
    ws[D_TRE + id] = tre;
    ws[D_GX + id]  = gx;
    ws[D_GY + id]  = gy;

    int meta = 0;
    if (valid || validp) {
        meta = gi | (gj << 8) | (bn << 16) | (am << 19)
             | (valid ? (1 << 24) : 0) | (validp ? (1 << 25) : 0)
             | ((((int)lab) & 7) << 26);
    }
    ((int*)ws)[D_META + id] = meta;
}

// ---------- K0: zero mask + accumulators, prep descriptors ----------
__global__ void __launch_bounds__(256) k_prep_zero(const float* __restrict__ tgt,
                                                   const float* __restrict__ anchors,
                                                   float* __restrict__ ws) {
    int gtid = blockIdx.x * 256 + threadIdx.x;
    if (gtid < NWORDS) ((unsigned int*)ws)[M_WORD + gtid] = 0u;
    if (gtid < 16) ((unsigned long long*)(ws + A_BASE))[gtid] = 0ull;
    if (gtid < NTGT) prep_one(gtid, tgt, anchors, ws);
}

// per-winner loss terms -> fixed-point atomics
__device__ __forceinline__ void add_win_terms(unsigned long long* A,
                                              const float* xp,
                                              float tx, float ty, float twv, float tlv,
                                              float timv, float trev, int lab) {
    float l[14];
    #pragma unroll
    for (int c = 0; c < 14; ++c) l[c] = xp[c * HW];
    float px = 1.f / (1.f + __expf(-l[0]));
    float py = 1.f / (1.f + __expf(-l[1]));
    float t0 = (px - tx) * (px - tx);
    float t1 = (py - ty) * (py - ty);
    float dw = l[2] - twv; float t2 = dw * dw;
    float dh = l[3] - tlv; float t3 = dh * dh;
    float di = l[4] - timv, dr = l[5] - trev;
    float t4 = di * di + dr * dr;
    float t5 = sp_f(-l[6]);
    float mx = l[7];
    #pragma unroll
    for (int c = 8; c < 14; ++c) mx = fmaxf(mx, l[c]);
    float e[7], se = 0.f;
    #pragma unroll
    for (int c = 0; c < 7; ++c) { e[c] = __expf(l[7 + c] - mx); se += e[c]; }
    float s[7], se2 = 0.f;
    #pragma unroll
    for (int c = 0; c < 7; ++c) { s[c] = e[c] / se; se2 += __expf(s[c]); }
    float t6 = __logf(se2) - s[lab];
    atomicAdd(&A[0], (unsigned long long)(long long)llrint((double)t0 * FXSCALE));
    atomicAdd(&A[1], (unsigned long long)(long long)llrint((double)t1 * FXSCALE));
    atomicAdd(&A[2], (unsigned long long)(long long)llrint((double)t2 * FXSCALE));
    atomicAdd(&A[3], (unsigned long long)(long long)llrint((double)t3 * FXSCALE));
    atomicAdd(&A[4], (unsigned long long)(long long)llrint((double)t4 * FXSCALE));
    atomicAdd(&A[5], (unsigned long long)(long long)llrint((double)t5 * FXSCALE));
    atomicAdd(&A[6], (unsigned long long)(long long)llrint((double)t6 * FXSCALE));
    atomicAdd(&A[7], 1ull);
}

// ---------- K1: everything, self-finalizing ----------
__global__ void __launch_bounds__(256) k_all(const float* __restrict__ x,
                                             const float* __restrict__ anchors,
                                             float* __restrict__ ws,
                                             float* __restrict__ out) {
    __shared__ double sd[256];
    __shared__ int    si[256];
    __shared__ float  sf[256];
    __shared__ int lastFlag;
    int tid = threadIdx.x, bx = blockIdx.x;
    unsigned long long* A = (unsigned long long*)(ws + A_BASE);
    unsigned int* mask = (unsigned int*)ws + M_WORD;
    const int* meta = (const int*)ws + D_META;

    if (bx < NSUM) {
        // ---- streaming grand sum of softplus(l6) over all cells ----
        int c4 = (bx * 256 + tid) * 4;
        int b = c4 / AHW;
        int within = c4 - b * AHW;
        int a = within / HW;
        int rem = within - a * HW;
        const float* p = x + (size_t)(b * CH + a * (7 + NC) + 6) * HW + rem;
        float4 v = *(const float4*)p;
        sf[tid] = sp_f(v.x) + sp_f(v.y) + sp_f(v.z) + sp_f(v.w);
        __syncthreads();
        for (int s = 128; s > 0; s >>= 1) {
            if (tid < s) sf[tid] += sf[tid + s];
            __syncthreads();
        }
        if (tid == 0) atomicExch(&((float*)ws)[SP_OFF + bx], sf[0]);
    } else if (bx < NSUM + NTGT) {
        // ---- per-target: overrides + winner loss + iou rect scatter ----
        int id = bx - NSUM;
        int b = id / NT;
        int mt = meta[id];
        double sub_acc = 0.0;
        int cnt_acc = 0;

        if (mt & (1 << 24)) {
            if (tid == 0) {
                int gi = mt & 255, gj = (mt >> 8) & 255;
                int bn = (mt >> 16) & 7, am = (mt >> 19) & 31;
                for (int a = 0; a < NA; ++a) {
                    if (((am >> a) & 1) || a == bn) {
                        int c = ((b * NA + a) * NH + gj) * NW + gi;
                        unsigned int old = atomicOr(&mask[c >> 5], 1u << (c & 31));
                        if (!((old >> (c & 31)) & 1u)) {
                            cnt_acc++;
                            float l6 = x[(size_t)(b * CH + a * (7 + NC) + 6) * HW + gj * NW + gi];
                            sub_acc += (double)sp_f(l6);
                        }
                    }
                }
            }
            if (tid == 1) {
                int t = id - b * NT;
                int key = mt & 0x7FFFF;
                bool winner = true;
                for (int t2 = t + 1; t2 < NT; ++t2) {
                    int m2 = meta[b * NT + t2];
                    if ((m2 & (1 << 24)) && ((m2 & 0x7FFFF) == key)) { winner = false; break; }
                }
                if (winner) {
                    int gi = mt & 255, gj = (mt >> 8) & 255;
                    int bn = (mt >> 16) & 7, lab = (mt >> 26) & 7;
                    const float* xp = x + (size_t)(b * CH + bn * (7 + NC)) * HW + gj * NW + gi;
                    add_win_terms(A, xp,
                                  ws[D_GX + id] - (float)gi, ws[D_GY + id] - (float)gj,
                                  ws[D_TW + id], ws[D_TL + id],
                                  ws[D_TIM + id], ws[D_TRE + id], lab);
                }
            }
        }
        if (mt & (1 << 25)) {
            float gxv = ws[D_GX + id], gyv = ws[D_GY + id];
            float tgw = ws[D_GW + id], tgl = ws[D_GL + id];
            float txlo = ws[D_XLO + id], txhi = ws[D_XHI + id];
            float tylo = ws[D_YLO + id], tyhi = ws[D_YHI + id];
            float tq = ws[D_Q + id];
            if (tgw > 0.f && tgl > 0.f) {
                float gw3 = tgw * (1.f / 3.f), gl3 = tgl * (1.f / 3.f);
                int i_lo = max(0, (int)floorf(gxv - gw3) - 1);
                int i_hi = min(NW - 1, (int)floorf(gxv + gw3) + 1);
                int j_lo = max(0, (int)floorf(gyv - gl3) - 1);
                int j_hi = min(NH - 1, (int)floorf(gyv + gl3) + 1);
                int W = i_hi - i_lo + 1, Hh = j_hi - j_lo + 1;
                int total = W * Hh * NA;
                for (int idx = tid; idx < total; idx += 256) {
                    int dx = idx % W;
                    int q = idx / W;
                    int j = j_lo + q % Hh;
                    int a = q / Hh;
                    int i = i_lo + dx;
                    const float* xp = x + (size_t)(b * CH + a * (7 + NC)) * HW + j * NW + i;
                    float l0 = xp[0], l1 = xp[HW], l2 = xp[2 * HW], l3 = xp[3 * HW];
                    float aw = anchors[2 * a], ah = anchors[2 * a + 1];
                    float bxv = (float)i + 1.f / (1.f + __expf(-l0));
                    float byv = (float)j + 1.f / (1.f + __expf(-l1));
                    float bw = __expf(l2) * aw;
                    float bh = __expf(l3) * ah;
                    float mxv = fminf(bxv - 0.5f * bw, txlo);
                    float Mxv = fmaxf(bxv + 0.5f * bw, txhi);
                    float myv = fminf(byv - 0.5f * bh, tylo);
                    float Myv = fmaxf(byv + 0.5f * bh, tyhi);
                    float cw = bw + tgw - (Mxv - mxv);
                    float chh = bh + tgl - (Myv - myv);
                    if (cw > 0.f && chh > 0.f && cw * chh > 0.375f * bw * bh + tq) {
                        int c = ((b * NA + a) * NH + j) * NW + i;
                        unsigned int old = atomicOr(&mask[c >> 5], 1u << (c & 31));
                        if (!((old >> (c & 31)) & 1u)) {
                            cnt_acc++;
                            sub_acc += (double)sp_f(xp[6 * HW]);
                        }
                    }
                }
            }
        }
        sd[tid] = sub_acc; si[tid] = cnt_acc;
        __syncthreads();
        for (int s = 128; s > 0; s >>= 1) {
            if (tid < s) { sd[tid] += sd[tid + s]; si[tid] += si[tid + s]; }
            __syncthreads();
        }
        if (tid == 0) {
            if (si[0] > 0) atomicAdd(&A[9], (unsigned long long)si[0]);
            if (sd[0] != 0.0)
                atomicAdd(&A[8], (unsigned long long)(long long)llrint(sd[0] * FXSCALE));
        }
    } else {
        // ---- c* block (np negative-index wrap cell) ----
        if (tid == 0) {
            int c = NCELL - 1;
            unsigned int old = atomicOr(&mask[c >> 5], 1u << (c & 31));
            if (!((old >> (c & 31)) & 1u)) {
                float l6 = x[(size_t)((NB - 1) * CH + (NA - 1) * (7 + NC) + 6) * HW + (HW - 1)];
                atomicAdd(&A[9], 1ull);
                atomicAdd(&A[8], (unsigned long long)(long long)llrint((double)sp_f(l6) * FXSCALE));
            }
        }
        if (tid == 1) {
            const float* xp = x + (size_t)((NB - 1) * CH + (NA - 1) * (7 + NC)) * HW + (HW - 1);
            float L16 = logf(1e-16f);
            add_win_terms(A, xp, 0.f, 0.f, L16, L16, 0.f, 0.f, 0);
        }
    }

    // ---- last-done block finalizes ----
    __threadfence();
    __syncthreads();
    if (tid == 0)
        lastFlag = (atomicAdd(&A[10], 1ull) == (unsigned long long)(GRID1 - 1));
    __syncthreads();
    if (lastFlag) {
        __threadfence();
        double p = 0.0;
        for (int i2 = tid; i2 < NSUM; i2 += 256)
            p += (double)((const float*)ws)[SP_OFF + i2];
        sd[tid] = p;
        __syncthreads();
        for (int s = 128; s > 0; s >>= 1) {
            if (tid < s) sd[tid] += sd[tid + s];
            __syncthreads();
        }
        if (tid == 0) {
            double stream_total = sd[0];
            double Aw[10];
            for (int k = 0; k < 10; ++k)
                Aw[k] = (double)(long long)atomicAdd(&A[k], 0ull);
            double nM  = fmax(Aw[7], 1.0);
            double sub = Aw[8] / FXSCALE;
            double scf = fmax((double)NCELL - Aw[9], 1.0);
            double bce = stream_total - sub;
            double loss =
                (Aw[0] + Aw[1] + Aw[2] + Aw[3] + Aw[4] + Aw[5]) / FXSCALE / nM
                + bce / scf
                + (1.0 / NB) * (Aw[6] / FXSCALE) / nM;
            out[0] = (float)loss;
        }
    }
}

// ---------- fallback path (proven round-2 kernels) ----------
__global__ void k_prep(const float* __restrict__ tgt,
                       const float* __restrict__ anchors,
                       float* __restrict__ ws) {
    int id = blockIdx.x * 256 + threadIdx.x;
    if (id >= NB * NT) return;
    prep_one(id, tgt, anchors, ws);
}

__global__ void __launch_bounds__(256) k_main(const float* __restrict__ x,
                                              const float* __restrict__ anchors,
                                              float* __restrict__ ws) {
    __shared__ float sxlo[NT], sxhi[NT], sylo[NT], syhi[NT];
    __shared__ float sgw[NT], sgl[NT], sq[NT];
    __shared__ int   smeta[NT];
    __shared__ float red0[256], red1[256];

    int b = blockIdx.y;
    int tid = threadIdx.x;
    if (tid < NT) {
        int id = b * NT + tid;
        sxlo[tid] = ws[D_XLO + id]; sxhi[tid] = ws[D_XHI + id];
        sylo[tid] = ws[D_YLO + id]; syhi[tid] = ws[D_YHI + id];
        sgw[tid]  = ws[D_GW + id];  sgl[tid]  = ws[D_GL + id];
        sq[tid]   = ws[D_Q + id];
        smeta[tid] = ((const int*)ws)[D_META + id];
    }
    __syncthreads();

    int p = blockIdx.x * 256 + tid;
    float s_cf = 0.f, s_bce = 0.f;
    if (p < AHW) {
        int a = p / HW;
        int rem = p - a * HW;
        int j = rem / NW;
        int i = rem - j * NW;
        const float* xp = x + (size_t)(b * CH + a * (7 + NC)) * HW + rem;
        float l0 = xp[0], l1 = xp[HW], l2 = xp[2 * HW], l3 = xp[3 * HW], l6 = xp[6 * HW];
        float aw = anchors[2 * a], ah = anchors[2 * a + 1];
        float px = 1.f / (1.f + __expf(-l0));
        float py = 1.f / (1.f + __expf(-l1));
        float bw = __expf(l2) * aw;
        float bh = __expf(l3) * ah;
        float bx = px + (float)i, by = py + (float)j;
        float bxlo = bx - 0.5f * bw, bxhi = bx + 0.5f * bw;
        float bylo = by - 0.5f * bh, byhi = by + 0.5f * bh;
        float qb = 0.375f * bw * bh;
        int ji = i | (j << 8);

        bool sawHigh = false, sawZero = false, sawOne = false;
        for (int t = 0; t < NT; ++t) {
            int mt = smeta[t];
            if (mt == 0) continue;
            if (mt & (1 << 25)) {
                float mx = fminf(bxlo, sxlo[t]);
                float Mx = fmaxf(bxhi, sxhi[t]);
                float my = fminf(bylo, sylo[t]);
                float My = fmaxf(byhi, syhi[t]);
                float cw = bw + sgw[t] - (Mx - mx);
                float chh = bh + sgl[t] - (My - my);
                if (cw > 0.f && chh > 0.f && cw * chh > qb + sq[t]) sawHigh = true;
            }
            if ((mt & (1 << 24)) && ((mt & 0xFFFF) == ji)) {
                if ((mt >> (19 + a)) & 1) sawZero = true;
                if (((mt >> 16) & 7) == a) sawOne = true;
            }
        }
        bool isCstar = (b == NB - 1) && (p == AHW - 1);
        if (!(sawHigh || sawZero || sawOne || isCstar)) {
            s_cf = 1.f;
            s_bce = (l6 > 20.f) ? l6 : __logf(1.f + __expf(l6));
        }
    }
    red0[tid] = s_cf; red1[tid] = s_bce;
    __syncthreads();
    for (int s = 128; s > 0; s >>= 1) {
        if (tid < s) { red0[tid] += red0[tid + s]; red1[tid] += red1[tid + s]; }
        __syncthreads();
    }
    if (tid == 0) {
        int blk = b * CELL_BLOCKS + blockIdx.x;
        ws[P_CF + blk] = red0[0];
        ws[P_CF + NBLK + blk] = red1[0];
    }
}

__global__ void __launch_bounds__(256) k_final(const float* __restrict__ x,
                                               const float* __restrict__ ws,
                                               float* __restrict__ out,
                                               int npart) {
    int tid = threadIdx.x;
    const int* meta = (const int*)ws + D_META;
    float v[8];
    for (int k = 0; k < 8; ++k) v[k] = 0.f;

    for (int id = tid; id < NB * NT; id += 256) {
        int mt = meta[id];
        if (!(mt & (1 << 24))) continue;
        int b = id / NT, t = id - b * NT;
        int key = mt & 0x7FFFF;
        bool winner = true;
        for (int t2 = t + 1; t2 < NT; ++t2) {
            int m2 = meta[b * NT + t2];
            if ((m2 & (1 << 24)) && ((m2 & 0x7FFFF) == key)) { winner = false; break; }
        }
        if (!winner) continue;

        int gi = mt & 255, gj = (mt >> 8) & 255;
        int bn = (mt >> 16) & 7, lab = (mt >> 26) & 7;
        const float* xp = x + (size_t)(b * CH + bn * (7 + NC)) * HW + gj * NW + gi;
        float l[14];
        for (int c = 0; c < 14; ++c) l[c] = xp[c * HW];

        float tx = ws[D_GX + id] - (float)gi;
        float ty = ws[D_GY + id] - (float)gj;
        float px = 1.f / (1.f + __expf(-l[0]));
        float py = 1.f / (1.f + __expf(-l[1]));
        v[0] += (px - tx) * (px - tx);
        v[1] += (py - ty) * (py - ty);
        float dw = l[2] - ws[D_TW + id]; v[2] += dw * dw;
        float dh = l[3] - ws[D_TL + id]; v[3] += dh * dh;
        float di = l[4] - ws[D_TIM + id];
        float dr = l[5] - ws[D_TRE + id];
        v[4] += di * di + dr * dr;
        float nl = -l[6];
        v[5] += (nl > 20.f) ? nl : __logf(1.f + __expf(nl));
        float mx = l[7];
        for (int c = 8; c < 14; ++c) mx = fmaxf(mx, l[c]);
        float e[7], se = 0.f;
        for (int c = 0; c < 7; ++c) { e[c] = __expf(l[7 + c] - mx); se += e[c]; }
        float s[7], se2 = 0.f;
        for (int c = 0; c < 7; ++c) { s[c] = e[c] / se; se2 += __expf(s[c]); }
        v[6] += __logf(se2) - s[lab];
        v[7] += 1.f;
    }

    if (tid == 0) {
        const float* xp = x + (size_t)((NB - 1) * CH + (NA - 1) * (7 + NC)) * HW + (HW - 1);
        float l[14];
        for (int c = 0; c < 14; ++c) l[c] = xp[c * HW];
        const float L16 = logf(1e-16f);
        float px = 1.f / (1.f + __expf(-l[0]));
        float py = 1.f / (1.f + __expf(-l[1]));
        v[0] += px * px;
        v[1] += py * py;
        float dw = l[2] - L16; v[2] += dw * dw;
        float dh = l[3] - L16; v[3] += dh * dh;
        v[4] += l[4] * l[4] + l[5] * l[5];
        float nl = -l[6];
        v[5] += (nl > 20.f) ? nl : __logf(1.f + __expf(nl));
        float mx = l[7];
        for (int c = 8; c < 14; ++c) mx = fmaxf(mx, l[c]);
        float e[7], se = 0.f;
        for (int c = 0; c < 7; ++c) { e[c] = __expf(l[7 + c] - mx); se += e[c]; }
        float s[7], se2 = 0.f;
        for (int c = 0; c < 7; ++c) { s[c] = e[c] / se; se2 += __expf(s[c]); }
        v[6] += __logf(se2) - s[0];
        v[7] += 1.f;
    }

    __shared__ float r[8][256];
    for (int k = 0; k < 8; ++k) r[k][tid] = v[k];
    __syncthreads();
    for (int st = 128; st > 0; st >>= 1) {
        if (tid < st)
            for (int k = 0; k < 8; ++k) r[k][tid] += r[k][tid + st];
        __syncthreads();
    }

    __shared__ double dcf[256], dbce[256];
    double acf = 0.0, abce = 0.0;
    for (int idx = tid; idx < npart; idx += 256) {
        acf += (double)ws[P_CF + idx];
        abce += (double)ws[P_CF + npart + idx];
    }
    dcf[tid] = acf; dbce[tid] = abce;
    __syncthreads();
    for (int st = 128; st > 0; st >>= 1) {
        if (tid < st) { dcf[tid] += dcf[tid + st]; dbce[tid] += dbce[tid + st]; }
        __syncthreads();
    }

    if (tid == 0) {
        double nM = fmax((double)r[7][0], 1.0);
        double scf = fmax(dcf[0], 1.0);
        double loss =
            ((double)r[0][0] + r[1][0] + r[2][0] + r[3][0] + r[4][0] + r[5][0]) / nM
            + dbce[0] / scf
            + (1.0 / NB) * (double)r[6][0] / nM;
        out[0] = (float)loss;
    }
}

extern "C" void kernel_launch(void* const* d_in, const int* in_sizes, int n_in,
                              void* d_out, int out_size, void* d_ws, size_t ws_size,
                              hipStream_t stream) {
    const float* x   = (const float*)d_in[0];
    const float* tgt = (const float*)d_in[1];
    const float* anc = (const float*)d_in[2];
    float* ws  = (float*)d_ws;
    float* out = (float*)d_out;

    if (ws_size >= (size_t)WS_NEED) {
        hipLaunchKernelGGL(k_prep_zero, dim3((NWORDS + 255) / 256), dim3(256), 0, stream,
                           tgt, anc, ws);
        hipLaunchKernelGGL(k_all, dim3(GRID1), dim3(256), 0, stream, x, anc, ws, out);
    } else {
        hipLaunchKernelGGL(k_prep, dim3((NB * NT + 255) / 256), dim3(256), 0, stream,
                           tgt, anc, ws);
        hipLaunchKernelGGL(k_main, dim3(CELL_BLOCKS, NB), dim3(256), 0, stream,
                           x, anc, ws);
        hipLaunchKernelGGL(k_final, dim3(1), dim3(256), 0, stream, x, ws, out, NBLK);
    }
}

// Round 5
// 32.314 us; speedup vs baseline: 7.0332x; 7.0332x over previous
//
#include <hip/hip_runtime.h>

#define NB 16
#define NT 50
#define NA 5
#define NH 152
#define NW 152
#define NC 7
#define CH 70            // NA*(7+NC)
#define HW (NH*NW)       // 23104
#define AHW (NA*HW)      // 115520
#define NCELL (NB*AHW)   // 1,848,320
#define NWORDS (NCELL/32) // 57,760
#define NTGT (NB*NT)      // 800

// fallback geometry
#define CELL_BLOCKS ((AHW + 255) / 256)   // 452
#define NBLK (CELL_BLOCKS * NB)           // 7232
// new-path geometry
#define SUM2_BLOCKS 452
#define SUM2_ITERS 4      // 452*256*4*4 >= NCELL (bounds-checked)

// ws float-offsets
#define D_XLO 0
#define D_XHI 800
#define D_YLO 1600
#define D_YHI 2400
#define D_GW  3200
#define D_GL  4000
#define D_Q   4800
#define D_TW  5600
#define D_TL  6400
#define D_TIM 7200
#define D_TRE 8000
#define D_GX  8800
#define D_GY  9600
#define D_META 10400     // int array
#define P_CF  11264      // fallback partials (overlaps M_WORD; paths exclusive)
#define M_WORD 16384     // u32 mask bits: [16384, 74144) words
#define W_OFF  74144     // 801 x 8 floats winner slots -> ends 80552
#define P2_OFF 80552     // 452 cf + 452 bce partials -> ends 81456
#define WS_NEED (81456 * 4)

__device__ __forceinline__ float sp_f(float v) {
    return (v > 20.f) ? v : __logf(1.f + __expf(v));
}

__device__ __forceinline__ void prep_one(int id, const float* __restrict__ tgt,
                                         const float* __restrict__ anchors,
                                         float* __restrict__ ws) {
    int b = id / NT, t = id - b * NT;
    const float* tp = tgt + id * 7;
    float lab = tp[0], cx = tp[1], cy = tp[2], w = tp[3], l = tp[4];
    float tim = tp[5], tre = tp[6];
    float sum = lab + cx + cy + w + l + tim + tre;
    bool valid = (sum != 0.0f);
    bool validp = true;
    const float* tb = tgt + (size_t)b * NT * 7;
    for (int t2 = 0; t2 <= t; ++t2) validp = validp && (tb[t2 * 7 + 1] != 0.0f);

    float gx = cx * NW, gy = cy * NH, gw = w * NW, gl = l * NH;
    int gi = (int)gx; gi = min(max(gi, 0), NW - 1);
    int gj = (int)gy; gj = min(max(gj, 0), NH - 1);

    float agt = (gw + 1.f) * (gl + 1.f);
    float best = -1.f; int bn = 0; int am = 0;
    float aw_b = 1.f, ah_b = 1.f;
    for (int a = 0; a < NA; ++a) {
        float aw = anchors[2 * a], ah = anchors[2 * a + 1];
        float iw = fmaxf(fminf(gw, aw) + 1.f, 0.f);
        float ih = fmaxf(fminf(gl, ah) + 1.f, 0.f);
        float inter = iw * ih;
        float aan = (aw + 1.f) * (ah + 1.f);
        float iou = inter / (agt + aan - inter + 1e-16f);
        if (iou > best) { best = iou; bn = a; aw_b = aw; ah_b = ah; }
        if (iou > 0.6f) am |= (1 << a);
    }

    ws[D_XLO + id] = gx - 0.5f * gw;
    ws[D_XHI + id] = gx + 0.5f * gw;
    ws[D_YLO + id] = gy - 0.5f * gl;
    ws[D_YHI + id] = gy + 0.5f * gl;
    ws[D_GW + id]  = gw;
    ws[D_GL + id]  = gl;
    ws[D_Q + id]   = 0.375f * gw * gl;
    ws[D_TW + id]  = logf(gw / aw_b + 1e-16f);
    ws[D_TL + id]  = logf(gl / ah_b + 1e-16f);
    ws[D_TIM + id] = tim;
    ws[D_TRE + id] = tre;
    ws[D_GX + id]  = gx;
    ws[D_GY + id]  = gy;

    int meta = 0;
    if (valid || validp) {
        meta = gi | (gj << 8) | (bn << 16) | (am << 19)
             | (valid ? (1 << 24) : 0) | (validp ? (1 << 25) : 0)
             | ((((int)lab) & 7) << 26);
    }
    ((int*)ws)[D_META + id] = meta;
}

// winner loss terms for one cell -> o[0..7] (7 terms + count)
__device__ __forceinline__ void win_terms(const float* __restrict__ xp,
                                          float tx, float ty, float twv, float tlv,
                                          float timv, float trev, int lab,
                                          float* __restrict__ o) {
    float l[14];
    #pragma unroll
    for (int c = 0; c < 14; ++c) l[c] = xp[c * HW];
    float px = 1.f / (1.f + __expf(-l[0]));
    float py = 1.f / (1.f + __expf(-l[1]));
    o[0] = (px - tx) * (px - tx);
    o[1] = (py - ty) * (py - ty);
    float dw = l[2] - twv; o[2] = dw * dw;
    float dh = l[3] - tlv; o[3] = dh * dh;
    float di = l[4] - timv, dr = l[5] - trev;
    o[4] = di * di + dr * dr;
    o[5] = sp_f(-l[6]);
    float mx = l[7];
    #pragma unroll
    for (int c = 8; c < 14; ++c) mx = fmaxf(mx, l[c]);
    float e[7], se = 0.f;
    #pragma unroll
    for (int c = 0; c < 7; ++c) { e[c] = __expf(l[7 + c] - mx); se += e[c]; }
    float s[7], se2 = 0.f;
    #pragma unroll
    for (int c = 0; c < 7; ++c) { s[c] = e[c] / se; se2 += __expf(s[c]); }
    o[6] = __logf(se2) - s[lab];
    o[7] = 1.f;
}

// ---------- K0: zero mask + prep descriptors ----------
__global__ void __launch_bounds__(256) k_prep_zero(const float* __restrict__ tgt,
                                                   const float* __restrict__ anchors,
                                                   float* __restrict__ ws) {
    int gtid = blockIdx.x * 256 + threadIdx.x;
    if (gtid < NWORDS) ((unsigned int*)ws)[M_WORD + gtid] = 0u;
    if (gtid < NTGT) prep_one(gtid, tgt, anchors, ws);
}

// ---------- K1: iou scatter (blocks 0..799) + winner eval (blocks 800..1600) ----------
__global__ void __launch_bounds__(256) k_scatter(const float* __restrict__ x,
                                                 const float* __restrict__ anchors,
                                                 float* __restrict__ ws) {
    int tid = threadIdx.x, bx = blockIdx.x;
    const int* meta = (const int*)ws + D_META;
    unsigned int* mask = (unsigned int*)ws + M_WORD;

    if (bx < NTGT) {
        // ---- iou rect scatter + overrides (proven round-3 body) ----
        int id = bx;
        int b = id / NT;
        int mt = meta[id];
        if (mt == 0) return;
        if ((mt & (1 << 24)) && tid == 0) {
            int gi = mt & 255, gj = (mt >> 8) & 255;
            int bn = (mt >> 16) & 7, am = (mt >> 19) & 31;
            for (int a = 0; a < NA; ++a) {
                if (((am >> a) & 1) || a == bn) {
                    int c = ((b * NA + a) * NH + gj) * NW + gi;
                    atomicOr(&mask[c >> 5], 1u << (c & 31));
                }
            }
        }
        if (!(mt & (1 << 25))) return;

        float gxv = ws[D_GX + id], gyv = ws[D_GY + id];
        float tgw = ws[D_GW + id], tgl = ws[D_GL + id];
        float txlo = ws[D_XLO + id], txhi = ws[D_XHI + id];
        float tylo = ws[D_YLO + id], tyhi = ws[D_YHI + id];
        float tq = ws[D_Q + id];
        if (tgw <= 0.f || tgl <= 0.f) return;

        // proven reach: pass => |bx-gx| < gw/3 and |by-gy| < gl/3 (+1 cell margin)
        float gw3 = tgw * (1.f / 3.f), gl3 = tgl * (1.f / 3.f);
        int i_lo = max(0, (int)floorf(gxv - gw3) - 1);
        int i_hi = min(NW - 1, (int)floorf(gxv + gw3) + 1);
        int j_lo = max(0, (int)floorf(gyv - gl3) - 1);
        int j_hi = min(NH - 1, (int)floorf(gyv + gl3) + 1);
        int W = i_hi - i_lo + 1, Hh = j_hi - j_lo + 1;
        int total = W * Hh * NA;
        for (int idx = tid; idx < total; idx += 256) {
            int dx = idx % W;
            int q = idx / W;
            int j = j_lo + q % Hh;
            int a = q / Hh;
            int i = i_lo + dx;
            const float* xp = x + (size_t)(b * CH + a * 14) * HW + j * NW + i;
            float l0 = xp[0], l1 = xp[HW], l2 = xp[2 * HW], l3 = xp[3 * HW];
            float aw = anchors[2 * a], ah = anchors[2 * a + 1];
            float bxv = (float)i + 1.f / (1.f + __expf(-l0));
            float byv = (float)j + 1.f / (1.f + __expf(-l1));
            float bw = __expf(l2) * aw;
            float bh = __expf(l3) * ah;
            float mxv = fminf(bxv - 0.5f * bw, txlo);
            float Mxv = fmaxf(bxv + 0.5f * bw, txhi);
            float myv = fminf(byv - 0.5f * bh, tylo);
            float Myv = fmaxf(byv + 0.5f * bh, tyhi);
            float cw = bw + tgw - (Mxv - mxv);
            float chh = bh + tgl - (Myv - myv);
            if (cw > 0.f && chh > 0.f && cw * chh > 0.375f * bw * bh + tq) {
                int c = ((b * NA + a) * NH + j) * NW + i;
                atomicOr(&mask[c >> 5], 1u << (c & 31));
            }
        }
    } else {
        // ---- winner blocks: one 8-float private slot each, no atomics ----
        int w = bx - NTGT;                 // 0..NTGT (NTGT == c* slot)
        __shared__ int lose;
        int mt = (w < NTGT) ? meta[w] : 0;
        if (tid == 0) lose = 0;
        __syncthreads();
        if (w < NTGT && (mt & (1 << 24))) {
            int b = w / NT, t = w - b * NT;
            int key = mt & 0x7FFFF;
            int t2 = t + 1 + tid;
            if (t2 < NT) {
                int m2 = meta[b * NT + t2];
                if ((m2 & (1 << 24)) && ((m2 & 0x7FFFF) == key)) lose = 1;  // benign race
            }
        }
        __syncthreads();
        if (tid == 0) {
            float slot[8] = {0.f, 0.f, 0.f, 0.f, 0.f, 0.f, 0.f, 0.f};
            if (w == NTGT) {
                // np negative-index wrap cell c*: last invalid row's values
                const float* xp = x + (size_t)((NB - 1) * CH + (NA - 1) * 14) * HW + (HW - 1);
                float L16 = logf(1e-16f);
                win_terms(xp, 0.f, 0.f, L16, L16, 0.f, 0.f, 0, slot);
            } else if ((mt & (1 << 24)) && !lose) {
                int b = w / NT;
                int gi = mt & 255, gj = (mt >> 8) & 255;
                int bn = (mt >> 16) & 7, lab = (mt >> 26) & 7;
                const float* xp = x + (size_t)(b * CH + bn * 14) * HW + gj * NW + gi;
                win_terms(xp, ws[D_GX + w] - (float)gi, ws[D_GY + w] - (float)gj,
                          ws[D_TW + w], ws[D_TL + w],
                          ws[D_TIM + w], ws[D_TRE + w], lab, slot);
            }
            float* dst = ws + W_OFF + w * 8;
            #pragma unroll
            for (int k = 0; k < 8; ++k) dst[k] = slot[k];
        }
    }
}

// ---------- K2: masked softplus(l6) sum, per-block partials ----------
__global__ void __launch_bounds__(256) k_sum2(const float* __restrict__ x,
                                              float* __restrict__ ws) {
    __shared__ float red0[256], red1[256];
    const unsigned int* mask = (const unsigned int*)ws + M_WORD;
    int tid = threadIdx.x;
    float s_cf = 0.f, s_bce = 0.f;
    for (int it = 0; it < SUM2_ITERS; ++it) {
        int c4 = (((it * SUM2_BLOCKS + blockIdx.x) * 256) + tid) * 4;
        if (c4 < NCELL) {
            int b = c4 / AHW;
            int within = c4 - b * AHW;
            int a = within / HW;
            int rem = within - a * HW;
            const float* p = x + (size_t)(b * CH + a * 14 + 6) * HW + rem;
            float4 v = *(const float4*)p;
            unsigned int word = mask[c4 >> 5];
            unsigned int sh = (unsigned)(c4 & 31);
            float lv[4] = {v.x, v.y, v.z, v.w};
            #pragma unroll
            for (int k = 0; k < 4; ++k) {
                bool excl = (word >> (sh + k)) & 1u;
                if (c4 + k == NCELL - 1) excl = true;   // c* is a mask cell
                if (!excl) { s_cf += 1.f; s_bce += sp_f(lv[k]); }
            }
        }
    }
    red0[tid] = s_cf; red1[tid] = s_bce;
    __syncthreads();
    for (int s = 128; s > 0; s >>= 1) {
        if (tid < s) { red0[tid] += red0[tid + s]; red1[tid] += red1[tid + s]; }
        __syncthreads();
    }
    if (tid == 0) {
        ws[P2_OFF + blockIdx.x] = red0[0];
        ws[P2_OFF + SUM2_BLOCKS + blockIdx.x] = red1[0];
    }
}

// ---------- K3: tiny deterministic reduce + loss assembly ----------
__global__ void __launch_bounds__(256) k_reduce(const float* __restrict__ ws,
                                                float* __restrict__ out) {
    int tid = threadIdx.x;
    double wv[8];
    #pragma unroll
    for (int k = 0; k < 8; ++k) wv[k] = 0.0;
    for (int s = tid; s < NTGT + 1; s += 256) {
        const float* sp = ws + W_OFF + s * 8;
        #pragma unroll
        for (int k = 0; k < 8; ++k) wv[k] += (double)sp[k];
    }
    __shared__ double R[8][256];
    #pragma unroll
    for (int k = 0; k < 8; ++k) R[k][tid] = wv[k];
    __syncthreads();
    for (int st = 128; st > 0; st >>= 1) {
        if (tid < st)
            #pragma unroll
            for (int k = 0; k < 8; ++k) R[k][tid] += R[k][tid + st];
        __syncthreads();
    }
    __shared__ double S[8];
    if (tid == 0)
        #pragma unroll
        for (int k = 0; k < 8; ++k) S[k] = R[k][0];
    __syncthreads();

    __shared__ double d0[256], d1[256];
    double acf = 0.0, abce = 0.0;
    for (int i = tid; i < SUM2_BLOCKS; i += 256) {
        acf += (double)ws[P2_OFF + i];
        abce += (double)ws[P2_OFF + SUM2_BLOCKS + i];
    }
    d0[tid] = acf; d1[tid] = abce;
    __syncthreads();
    for (int st = 128; st > 0; st >>= 1) {
        if (tid < st) { d0[tid] += d0[tid + st]; d1[tid] += d1[tid + st]; }
        __syncthreads();
    }
    if (tid == 0) {
        double nM  = fmax(S[7], 1.0);
        double scf = fmax(d0[0], 1.0);
        double loss =
            (S[0] + S[1] + S[2] + S[3] + S[4] + S[5]) / nM
            + d1[0] / scf
            + (1.0 / NB) * S[6] / nM;
        out[0] = (float)loss;
    }
}

// ---------- fallback path (proven round-2 kernels) ----------
__global__ void k_prep(const float* __restrict__ tgt,
                       const float* __restrict__ anchors,
                       float* __restrict__ ws) {
    int id = blockIdx.x * 256 + threadIdx.x;
    if (id >= NB * NT) return;
    prep_one(id, tgt, anchors, ws);
}

__global__ void __launch_bounds__(256) k_main(const float* __restrict__ x,
                                              const float* __restrict__ anchors,
                                              float* __restrict__ ws) {
    __shared__ float sxlo[NT], sxhi[NT], sylo[NT], syhi[NT];
    __shared__ float sgw[NT], sgl[NT], sq[NT];
    __shared__ int   smeta[NT];
    __shared__ float red0[256], red1[256];

    int b = blockIdx.y;
    int tid = threadIdx.x;
    if (tid < NT) {
        int id = b * NT + tid;
        sxlo[tid] = ws[D_XLO + id]; sxhi[tid] = ws[D_XHI + id];
        sylo[tid] = ws[D_YLO + id]; syhi[tid] = ws[D_YHI + id];
        sgw[tid]  = ws[D_GW + id];  sgl[tid]  = ws[D_GL + id];
        sq[tid]   = ws[D_Q + id];
        smeta[tid] = ((const int*)ws)[D_META + id];
    }
    __syncthreads();

    int p = blockIdx.x * 256 + tid;
    float s_cf = 0.f, s_bce = 0.f;
    if (p < AHW) {
        int a = p / HW;
        int rem = p - a * HW;
        int j = rem / NW;
        int i = rem - j * NW;
        const float* xp = x + (size_t)(b * CH + a * 14) * HW + rem;
        float l0 = xp[0], l1 = xp[HW], l2 = xp[2 * HW], l3 = xp[3 * HW], l6 = xp[6 * HW];
        float aw = anchors[2 * a], ah = anchors[2 * a + 1];
        float px = 1.f / (1.f + __expf(-l0));
        float py = 1.f / (1.f + __expf(-l1));
        float bw = __expf(l2) * aw;
        float bh = __expf(l3) * ah;
        float bx = px + (float)i, by = py + (float)j;
        float bxlo = bx - 0.5f * bw, bxhi = bx + 0.5f * bw;
        float bylo = by - 0.5f * bh, byhi = by + 0.5f * bh;
        float qb = 0.375f * bw * bh;
        int ji = i | (j << 8);

        bool sawHigh = false, sawZero = false, sawOne = false;
        for (int t = 0; t < NT; ++t) {
            int mt = smeta[t];
            if (mt == 0) continue;
            if (mt & (1 << 25)) {
                float mx = fminf(bxlo, sxlo[t]);
                float Mx = fmaxf(bxhi, sxhi[t]);
                float my = fminf(bylo, sylo[t]);
                float My = fmaxf(byhi, syhi[t]);
                float cw = bw + sgw[t] - (Mx - mx);
                float chh = bh + sgl[t] - (My - my);
                if (cw > 0.f && chh > 0.f && cw * chh > qb + sq[t]) sawHigh = true;
            }
            if ((mt & (1 << 24)) && ((mt & 0xFFFF) == ji)) {
                if ((mt >> (19 + a)) & 1) sawZero = true;
                if (((mt >> 16) & 7) == a) sawOne = true;
            }
        }
        bool isCstar = (b == NB - 1) && (p == AHW - 1);
        if (!(sawHigh || sawZero || sawOne || isCstar)) {
            s_cf = 1.f;
            s_bce = (l6 > 20.f) ? l6 : __logf(1.f + __expf(l6));
        }
    }
    red0[tid] = s_cf; red1[tid] = s_bce;
    __syncthreads();
    for (int s = 128; s > 0; s >>= 1) {
        if (tid < s) { red0[tid] += red0[tid + s]; red1[tid] += red1[tid + s]; }
        __syncthreads();
    }
    if (tid == 0) {
        int blk = b * CELL_BLOCKS + blockIdx.x;
        ws[P_CF + blk] = red0[0];
        ws[P_CF + NBLK + blk] = red1[0];
    }
}

__global__ void __launch_bounds__(256) k_final(const float* __restrict__ x,
                                               const float* __restrict__ ws,
                                               float* __restrict__ out,
                                               int npart) {
    int tid = threadIdx.x;
    const int* meta = (const int*)ws + D_META;
    float v[8];
    for (int k = 0; k < 8; ++k) v[k] = 0.f;

    for (int id = tid; id < NB * NT; id += 256) {
        int mt = meta[id];
        if (!(mt & (1 << 24))) continue;
        int b = id / NT, t = id - b * NT;
        int key = mt & 0x7FFFF;
        bool winner = true;
        for (int t2 = t + 1; t2 < NT; ++t2) {
            int m2 = meta[b * NT + t2];
            if ((m2 & (1 << 24)) && ((m2 & 0x7FFFF) == key)) { winner = false; break; }
        }
        if (!winner) continue;

        int gi = mt & 255, gj = (mt >> 8) & 255;
        int bn = (mt >> 16) & 7, lab = (mt >> 26) & 7;
        const float* xp = x + (size_t)(b * CH + bn * 14) * HW + gj * NW + gi;
        float o[8];
        win_terms(xp, ws[D_GX + id] - (float)gi, ws[D_GY + id] - (float)gj,
                  ws[D_TW + id], ws[D_TL + id],
                  ws[D_TIM + id], ws[D_TRE + id], lab, o);
        for (int k = 0; k < 7; ++k) v[k] += o[k];
        v[7] += 1.f;
    }

    if (tid == 0) {
        const float* xp = x + (size_t)((NB - 1) * CH + (NA - 1) * 14) * HW + (HW - 1);
        float L16 = logf(1e-16f);
        float o[8];
        win_terms(xp, 0.f, 0.f, L16, L16, 0.f, 0.f, 0, o);
        for (int k = 0; k < 7; ++k) v[k] += o[k];
        v[7] += 1.f;
    }

    __shared__ float r[8][256];
    for (int k = 0; k < 8; ++k) r[k][tid] = v[k];
    __syncthreads();
    for (int st = 128; st > 0; st >>= 1) {
        if (tid < st)
            for (int k = 0; k < 8; ++k) r[k][tid] += r[k][tid + st];
        __syncthreads();
    }

    __shared__ double dcf[256], dbce[256];
    double acf = 0.0, abce = 0.0;
    for (int idx = tid; idx < npart; idx += 256) {
        acf += (double)ws[P_CF + idx];
        abce += (double)ws[P_CF + npart + idx];
    }
    dcf[tid] = acf; dbce[tid] = abce;
    __syncthreads();
    for (int st = 128; st > 0; st >>= 1) {
        if (tid < st) { dcf[tid] += dcf[tid + st]; dbce[tid] += dbce[tid + st]; }
        __syncthreads();
    }

    if (tid == 0) {
        double nM = fmax((double)r[7][0], 1.0);
        double scf = fmax(dcf[0], 1.0);
        double loss =
            ((double)r[0][0] + r[1][0] + r[2][0] + r[3][0] + r[4][0] + r[5][0]) / nM
            + dbce[0] / scf
            + (1.0 / NB) * (double)r[6][0] / nM;
        out[0] = (float)loss;
    }
}

extern "C" void kernel_launch(void* const* d_in, const int* in_sizes, int n_in,
                              void* d_out, int out_size, void* d_ws, size_t ws_size,
                              hipStream_t stream) {
    const float* x   = (const float*)d_in[0];
    const float* tgt = (const float*)d_in[1];
    const float* anc = (const float*)d_in[2];
    float* ws  = (float*)d_ws;
    float* out = (float*)d_out;

    if (ws_size >= (size_t)WS_NEED) {
        hipLaunchKernelGGL(k_prep_zero, dim3((NWORDS + 255) / 256), dim3(256), 0, stream,
                           tgt, anc, ws);
        hipLaunchKernelGGL(k_scatter, dim3(2 * NTGT + 1), dim3(256), 0, stream,
                           x, anc, ws);
        hipLaunchKernelGGL(k_sum2, dim3(SUM2_BLOCKS), dim3(256), 0, stream, x, ws);
        hipLaunchKernelGGL(k_reduce, dim3(1), dim3(256), 0, stream, ws, out);
    } else {
        hipLaunchKernelGGL(k_prep, dim3((NB * NT + 255) / 256), dim3(256), 0, stream,
                           tgt, anc, ws);
        hipLaunchKernelGGL(k_main, dim3(CELL_BLOCKS, NB), dim3(256), 0, stream,
                           x, anc, ws);
        hipLaunchKernelGGL(k_final, dim3(1), dim3(256), 0, stream, x, ws, out, NBLK);
    }
}